// Round 14
// baseline (1189.531 us; speedup 1.0000x reference)
//
#include <hip/hip_runtime.h>
#include <hip/hip_bf16.h>
#include <cstddef>
#include <cstdint>

typedef __attribute__((ext_vector_type(8))) short v8s;     // 8 bf16 (4 VGPR)
typedef __attribute__((ext_vector_type(16))) float v16f;   // MFMA 32x32 acc

#define GLDS(SRC, DST) __builtin_amdgcn_global_load_lds( \
    (const __attribute__((address_space(1))) void*)(SRC), \
    (__attribute__((address_space(3))) void*)(DST), 16, 0, 0)

#define WAIT_VM0() asm volatile("s_waitcnt vmcnt(0)" ::: "memory")
#define SCHED0()   __builtin_amdgcn_sched_barrier(0)

// RNE fp32 -> bf16 split: x ~= hi + lo, |x - hi - lo| <~ 2^-18 |x|
__device__ __forceinline__ void bf16split(float x, unsigned short& h, unsigned short& l) {
    union { float f; unsigned u; } a; a.f = x;
    unsigned r = a.u + 0x7fff + ((a.u >> 16) & 1);
    h = (unsigned short)(r >> 16);
    union { unsigned u; float f; } hb; hb.u = (unsigned)h << 16;
    union { float f; unsigned u; } b; b.f = x - hb.f;
    unsigned r2 = b.u + 0x7fff + ((b.u >> 16) & 1);
    l = (unsigned short)(r2 >> 16);
}

// ---------------------------------------------------------------------------
// prep (R8 form, measured-best): wT1[k*256+oc] = conv1_w[oc*81+k]
// wpk: 648 slabs (g 0..7, k 0..80) of 32 KB = 64 rows x 512 B, GLDS-linear
// pre-swizzled: byte D: R=D>>9, v=(D&511)^((R&31)<<4), h=v>>7, pl=(v>>6)&1,
// icb=v&63 -> ch=64h+R, ic=g*32+icb/2, plane pl of split(pw[ch][ic][k]).
// ---------------------------------------------------------------------------
__global__ __launch_bounds__(256) void prep_kernel(
    const float* __restrict__ cw, const float* __restrict__ pw,
    float* __restrict__ wT1, char* __restrict__ wpk)
{
    int idx = blockIdx.x * 256 + threadIdx.x;
    if (idx < 81 * 256) {
        int k = idx >> 8, oc = idx & 255;
        wT1[idx] = cw[oc * 81 + k];
    }
    int Q = idx & 2047;
    int slab = idx >> 11;                 // 0..647
    int D = Q << 4;
    int R = D >> 9;                       // 0..63
    int v = (D & 511) ^ ((R & 31) << 4);
    int h = v >> 7, pl = (v >> 6) & 1, icb = v & 63;
    int ch = h * 64 + R;
    int g = slab / 81, k = slab - g * 81;
    int ic0 = g * 32 + (icb >> 1);
    const float* src = pw + ((size_t)ch * 256 + ic0) * 81 + k;
    v8s ov;
#pragma unroll
    for (int j = 0; j < 8; ++j) {
        unsigned short hh, ll; bf16split(src[(size_t)j * 81], hh, ll);
        ov[j] = (short)(pl ? ll : hh);
    }
    *(v8s*)(wpk + (size_t)slab * 32768 + D) = ov;
}

// ---------------------------------------------------------------------------
// conv1 (register-tiled): [B,1,28,28] -> xc2 rows of 1024 B [hi 256][lo 256]
// ---------------------------------------------------------------------------
__global__ __launch_bounds__(256) void conv1_kernel(
    const float* __restrict__ img,   // [B][784]
    const float* __restrict__ wT1,   // [81][256]
    const float* __restrict__ bias,  // [256]
    char* __restrict__ xc2,          // [bc][400][1024 B]
    int b0)
{
    const int bl = blockIdx.x;
    const int oc = threadIdx.x;
    __shared__ __align__(16) float im[784];
    const float* ib = img + (size_t)(b0 + bl) * 784;
    for (int e = oc; e < 784; e += 256) im[e] = ib[e];
    float w[81];
#pragma unroll
    for (int k = 0; k < 81; ++k) w[k] = wT1[k * 256 + oc];
    float bv = bias[oc];
    __syncthreads();
    char* ob = xc2 + (size_t)bl * 409600;
    for (int oy = 0; oy < 20; ++oy) {
        float a[20];
#pragma unroll
        for (int ox = 0; ox < 20; ++ox) a[ox] = bv;
        for (int ky = 0; ky < 9; ++ky) {
            const float* rp = &im[(oy + ky) * 28];
            float r[28];
#pragma unroll
            for (int q = 0; q < 7; ++q) {
                float4 v4 = *(const float4*)(rp + q * 4);
                r[q * 4] = v4.x; r[q * 4 + 1] = v4.y;
                r[q * 4 + 2] = v4.z; r[q * 4 + 3] = v4.w;
            }
#pragma unroll
            for (int kx = 0; kx < 9; ++kx) {
                float wv = w[ky * 9 + kx];
#pragma unroll
                for (int ox = 0; ox < 20; ++ox)
                    a[ox] = fmaf(wv, r[ox + kx], a[ox]);
            }
        }
#pragma unroll
        for (int ox = 0; ox < 20; ++ox) {
            float av = fmaxf(a[ox], 0.f);
            unsigned short h, l; bf16split(av, h, l);
            char* rp2 = ob + (size_t)(oy * 20 + ox) * 1024;
            *(unsigned short*)(rp2 + oc * 2) = h;
            *(unsigned short*)(rp2 + 512 + oc * 2) = l;
        }
    }
}

// ---------------------------------------------------------------------------
// primary conv implicit GEMM, split-bf16 (3 products), split-K x8, g-SLOWEST
// grid. BM=192 x BN=256, 8 waves (wm=w&1 / 96 m-rows, wn=w>>1 / 64 ch),
// wave-tile 96x64. R13 engine + m201-style 4-PHASE schedule per K-step:
// phase (s,fn) = {1-2 stage-GLDS ; ds_read phase frags ; s_barrier ;
// setprio(1) ; 9 MFMA ; setprio(0) ; s_barrier}. Phase p's MFMA overlaps
// phase p+1's LDS issue across waves (role-split, T3/T5). One vmcnt(0)
// drain per step (dbuf swap); stage(k+1) spread over the 4 phases.
// ---------------------------------------------------------------------------
__global__ __launch_bounds__(512, 1) void gemm_kernel(
    const char* __restrict__ xc2,   // [bc][400][1024 B]
    const char* __restrict__ wpk,   // [648 slabs][32 KB]
    float* __restrict__ prim,       // [B*36][256], pre-zeroed
    int M, int Mtiles, int gm0)     // M = bc*36 local; gm0 = b0*36
{
    __shared__ __align__(128) char As[2][24576];
    __shared__ __align__(128) char Bs[2][32768];
    const int tid = threadIdx.x;
    const int w = tid >> 6, lane = tid & 63;
    const int wm = w & 1, wn = w >> 1;
    const int col = lane & 31, kg = lane >> 5;
    const int id = blockIdx.x;
    const int g = id / Mtiles;
    const int tile = id - g * Mtiles;
    const int m0 = tile * 192;

    // A-gather per-lane constants (3 GLDS of 1 KB per wave)
    int pbase[3], asrc[3];
#pragma unroll
    for (int i = 0; i < 3; ++i) {
        int d = (w * 3 + i) * 1024 + lane * 16;    // 0..24575
        int R = d >> 9;                            // 0..47
        int v = (d & 511) ^ ((R & 31) << 4);
        int h = v >> 7, pl = (v >> 6) & 1, icb = v & 63;
        int m = m0 + 48 * h + R; if (m >= M) m = M - 1;
        int b = m / 36, s6 = m - b * 36;
        pbase[i] = b * 400 + (s6 / 6) * 40 + (s6 % 6) * 2;
        asrc[i] = pl * 512 + g * 64 + icb;
    }
    // A fragment-read constants: m = wm*96 + fm*32 + col
    int Abase[3], Ahof[3], Axor[3];
#pragma unroll
    for (int fm = 0; fm < 3; ++fm) {
        int m = wm * 96 + fm * 32 + col;
        int h = m / 48, R = m - h * 48;
        Abase[fm] = R * 512;
        Ahof[fm] = h * 128;
        Axor[fm] = (R & 31) << 4;
    }
    const char* wg = wpk + (size_t)g * 81 * 32768;

    v16f acc[3][2];
#pragma unroll
    for (int i = 0; i < 3; ++i)
#pragma unroll
        for (int j = 0; j < 2; ++j)
#pragma unroll
            for (int e = 0; e < 16; ++e) acc[i][j][e] = 0.f;

    auto gldsA = [&](int nb, int kk, int i) {
        const int koff = (kk / 9) * 20 + (kk % 9);
        GLDS(xc2 + (size_t)(pbase[i] + koff) * 1024 + asrc[i],
             &As[nb][(w * 3 + i) * 1024]);
    };
    auto gldsB = [&](int nb, int kk, int i) {
        const char* bs = wg + (size_t)kk * 32768;
        GLDS(bs + (w * 4 + i) * 1024 + lane * 16,
             &Bs[nb][(w * 4 + i) * 1024]);
    };

    // prologue: full stage of step 0
#pragma unroll
    for (int i = 0; i < 3; ++i) gldsA(0, 0, i);
#pragma unroll
    for (int i = 0; i < 4; ++i) gldsB(0, 0, i);
    WAIT_VM0(); SCHED0();
    __builtin_amdgcn_s_barrier(); SCHED0();

    const int xr = col << 4;
    for (int k = 0; k < 81; ++k) {
        const int cur = k & 1, nxt = cur ^ 1;
        const bool st = (k < 80);
        const char* Ab = &As[cur][0];
        const char* Bb = &Bs[cur][0];
        v8s Ah[3], Al[3];

#pragma unroll
        for (int p = 0; p < 4; ++p) {
            const int s = p >> 1, fn = p & 1;
            const int vb = s * 32 + kg * 16;
            // stage portion for step k+1 (3 A + 4 B spread over 4 phases)
            if (st) {
                if (p == 0) { gldsA(nxt, k + 1, 0); gldsA(nxt, k + 1, 1); }
                else if (p == 1) { gldsA(nxt, k + 1, 2); gldsB(nxt, k + 1, 0); }
                else if (p == 2) { gldsB(nxt, k + 1, 1); gldsB(nxt, k + 1, 2); }
                else { gldsB(nxt, k + 1, 3); }
            }
            // phase fragment reads
            if (fn == 0) {
#pragma unroll
                for (int fm = 0; fm < 3; ++fm) {
                    const char* ap = Ab + Abase[fm];
                    Ah[fm] = *(const v8s*)(ap + ((Ahof[fm] + vb) ^ Axor[fm]));
                    Al[fm] = *(const v8s*)(ap + ((Ahof[fm] + 64 + vb) ^ Axor[fm]));
                }
            }
            const char* bp = Bb + (fn * 32 + col) * 512;
            v8s Bh = *(const v8s*)(bp + ((wn * 128 + vb) ^ xr));
            v8s Bl = *(const v8s*)(bp + ((wn * 128 + 64 + vb) ^ xr));

            __builtin_amdgcn_s_barrier();
            SCHED0();
            __builtin_amdgcn_s_setprio(1);
#pragma unroll
            for (int fm = 0; fm < 3; ++fm) {
                acc[fm][fn] = __builtin_amdgcn_mfma_f32_32x32x16_bf16(Al[fm], Bh, acc[fm][fn], 0, 0, 0);
                acc[fm][fn] = __builtin_amdgcn_mfma_f32_32x32x16_bf16(Ah[fm], Bl, acc[fm][fn], 0, 0, 0);
                acc[fm][fn] = __builtin_amdgcn_mfma_f32_32x32x16_bf16(Ah[fm], Bh, acc[fm][fn], 0, 0, 0);
            }
            __builtin_amdgcn_s_setprio(0);
            SCHED0();
            if (p < 3) {
                __builtin_amdgcn_s_barrier();
            } else if (st) {
                // step-end: drain stage(k+1) before swapping buffers
                WAIT_VM0(); SCHED0();
                __builtin_amdgcn_s_barrier(); SCHED0();
            }
        }
    }

    // epilogue: atomic accumulate into the single prim plane (global m)
    float* pg = prim + (size_t)gm0 * 256;
#pragma unroll
    for (int fm = 0; fm < 3; ++fm)
#pragma unroll
        for (int fn = 0; fn < 2; ++fn) {
            int ch = wn * 64 + fn * 32 + col;
#pragma unroll
            for (int rg = 0; rg < 16; ++rg) {
                int row = (rg & 3) + 8 * (rg >> 2) + 4 * kg;
                int m = m0 + wm * 96 + fm * 32 + row;
                if (m < M) atomicAdd(&pg[(size_t)m * 256 + ch], acc[fm][fn][rg]);
            }
        }
}

// ---------------------------------------------------------------------------
// prim (1 plane, full batch) -> +bias -> regroup -> squash -> u [B][1152][8]
// ---------------------------------------------------------------------------
__global__ __launch_bounds__(256) void prim2u_kernel(
    const float* __restrict__ prim, const float* __restrict__ pb,
    float* __restrict__ u, int M)
{
    __shared__ float p[64 * 257];    // 65.8 KB
    __shared__ float bsh[256];
    const int tid = threadIdx.x;
    const int rows0 = blockIdx.x * 64;
    bsh[tid] = pb[tid];
#pragma unroll
    for (int j = 0; j < 16; ++j) {
        int e4 = j * 256 + tid;
        int row = e4 >> 6, c4 = (e4 & 63) << 2;
        int rr = rows0 + row; if (rr >= M) rr = M - 1;
        float4 a = *(const float4*)(prim + (size_t)rr * 256 + c4);
        float* pp = &p[row * 257 + c4];
        pp[0] = a.x; pp[1] = a.y; pp[2] = a.z; pp[3] = a.w;
    }
    __syncthreads();
#pragma unroll
    for (int j = 0; j < 8; ++j) {
        int idx = j * 256 + tid;          // 64 rows x 32 cc
        int row = idx & 63, cc = idx >> 6;
        int m = rows0 + row;
        if (m >= M) continue;
        int b = m / 36, s = m - b * 36;
        float p8[8]; float sn = 0.f;
#pragma unroll
        for (int d = 0; d < 8; ++d) {
            float v = p[row * 257 + d * 32 + cc] + bsh[d * 32 + cc];
            p8[d] = v; sn += v * v;
        }
        float fac = sqrtf(sn) / (1.0f + sn);
        float4 o0, o1;
        o0.x = fac * p8[0]; o0.y = fac * p8[1]; o0.z = fac * p8[2]; o0.w = fac * p8[3];
        o1.x = fac * p8[4]; o1.y = fac * p8[5]; o1.z = fac * p8[6]; o1.w = fac * p8[7];
        float* up = u + ((size_t)b * 1152 + cc * 36 + s) * 8;
        *(float4*)up = o0;
        *(float4*)(up + 4) = o1;
    }
}

// ---------------------------------------------------------------------------
// routing (R8 form, measured-best): one block per (b-pair, c), 512 thr,
// u_hat TRANSPOSED in LDS ([16][1152] per image, conflict-free).
// ---------------------------------------------------------------------------
__global__ __launch_bounds__(512) void routing_kernel(
    const float* __restrict__ u,   // [B][1152][8]
    const float* __restrict__ W,   // [10][1152][8][16]
    float* __restrict__ out,       // [B][10][16]
    int B)
{
    const int b0 = blockIdx.x * 2;
    const int c = blockIdx.y;
    const int tid = threadIdx.x;
    __shared__ float uht[2][16][1152];    // 147456 B
    __shared__ float bijs[2][1152];       // 9216 B
    __shared__ float red[2][4 * 17];
    __shared__ float sred[2][17];
    __shared__ float mred[2][4];

    const float* __restrict__ Wc = W + (size_t)c * (1152 * 128);
    const int b1 = (b0 + 1 < B) ? b0 + 1 : b0;
    const float* __restrict__ ub0 = u + (size_t)b0 * 9216;
    const float* __restrict__ ub1 = u + (size_t)b1 * 9216;

    for (int n = tid; n < 1152; n += 512) {
        const float4* p0 = (const float4*)(ub0 + n * 8);
        const float4* p1 = (const float4*)(ub1 + n * 8);
        float4 a0 = p0[0], a1 = p0[1], c0 = p1[0], c1 = p1[1];
        float uu0[8] = {a0.x, a0.y, a0.z, a0.w, a1.x, a1.y, a1.z, a1.w};
        float uu1[8] = {c0.x, c0.y, c0.z, c0.w, c1.x, c1.y, c1.z, c1.w};
        float acc0[16], acc1[16];
#pragma unroll
        for (int o = 0; o < 16; ++o) { acc0[o] = 0.f; acc1[o] = 0.f; }
        const float* wn = Wc + n * 128;
#pragma unroll
        for (int i = 0; i < 8; ++i)
#pragma unroll
            for (int o = 0; o < 16; ++o) {
                float wv = wn[i * 16 + o];
                acc0[o] = fmaf(uu0[i], wv, acc0[o]);
                acc1[o] = fmaf(uu1[i], wv, acc1[o]);
            }
#pragma unroll
        for (int o = 0; o < 16; ++o) { uht[0][o][n] = acc0[o]; uht[1][o][n] = acc1[o]; }
        bijs[0][n] = 0.f; bijs[1][n] = 0.f;
    }
    __syncthreads();

    const int img = tid >> 8, t = tid & 255;
    const int wid = t >> 6, lane = t & 63;
    const float* __restrict__ UHT = &uht[img][0][0];
    float* __restrict__ bij = bijs[img];
    float* __restrict__ redi = red[img];
    float* __restrict__ sredi = sred[img];
    float* __restrict__ mredi = mred[img];

    float fac = 0.f, inv = 0.f;
    for (int it = 0; it < 3; ++it) {
        float m = -3.4e38f;
        for (int n = t; n < 1152; n += 256) m = fmaxf(m, bij[n]);
#pragma unroll
        for (int off = 32; off > 0; off >>= 1) m = fmaxf(m, __shfl_down(m, off));
        if (lane == 0) mredi[wid] = m;
        __syncthreads();
        float M = fmaxf(fmaxf(mredi[0], mredi[1]), fmaxf(mredi[2], mredi[3]));
        float se = 0.f;
        float sp[16];
#pragma unroll
        for (int o = 0; o < 16; ++o) sp[o] = 0.f;
        for (int n = t; n < 1152; n += 256) {
            float e = expf(bij[n] - M);
            se += e;
#pragma unroll
            for (int o = 0; o < 16; ++o) sp[o] = fmaf(e, UHT[o * 1152 + n], sp[o]);
        }
#pragma unroll
        for (int o = 0; o < 16; ++o)
#pragma unroll
            for (int off = 32; off > 0; off >>= 1) sp[o] += __shfl_down(sp[o], off);
#pragma unroll
        for (int off = 32; off > 0; off >>= 1) se += __shfl_down(se, off);
        if (lane == 0) {
#pragma unroll
            for (int o = 0; o < 16; ++o) redi[wid * 17 + o] = sp[o];
            redi[wid * 17 + 16] = se;
        }
        __syncthreads();
        if (t < 17)
            sredi[t] = redi[t] + redi[17 + t] + redi[34 + t] + redi[51 + t];
        __syncthreads();
        inv = 1.0f / sredi[16];
        float sn = 0.f;
        float sj[16];
#pragma unroll
        for (int o = 0; o < 16; ++o) { sj[o] = sredi[o] * inv; sn = fmaf(sj[o], sj[o], sn); }
        fac = sqrtf(sn) / (1.0f + sn);
        if (it < 2) {
            float v[16];
#pragma unroll
            for (int o = 0; o < 16; ++o) v[o] = fac * sj[o];
            for (int n = t; n < 1152; n += 256) {
                float a = 0.f;
#pragma unroll
                for (int o = 0; o < 16; ++o) a = fmaf(UHT[o * 1152 + n], v[o], a);
                bij[n] += a;
            }
        }
        __syncthreads();
    }
    if (t < 16 && b0 + img < B)
        out[((size_t)(b0 + img) * 10 + c) * 16 + t] = fac * (sredi[t] * inv);
}

// ---------------------------------------------------------------------------
extern "C" void kernel_launch(void* const* d_in, const int* in_sizes, int n_in,
                              void* d_out, int out_size, void* d_ws, size_t ws_size,
                              hipStream_t stream) {
    const float* images  = (const float*)d_in[0];
    const float* conv1_w = (const float*)d_in[1];
    const float* conv1_b = (const float*)d_in[2];
    const float* prim_w  = (const float*)d_in[3];
    const float* prim_b  = (const float*)d_in[4];
    const float* W       = (const float*)d_in[5];
    float* out = (float*)d_out;

    const int B = in_sizes[0] / 784;
    const int Mg = B * 36;
    const size_t usz = (size_t)B * 1152 * 8 * 4;      // 18.9 MB @ B=512
    const size_t xc2_full = (size_t)B * 409600;       // 209.7 MB @ B=512

    char* wsb = (char*)d_ws;
    size_t off = 0;
    float* wT1 = (float*)(wsb + off);
    off += 81 * 256 * 4;
    off = (off + 1023) & ~(size_t)1023;
    char* wpk = wsb + off;
    off += (size_t)648 * 32768;                  // 21.2 MB
    float* prim = (float*)(wsb + off);
    off += (size_t)Mg * 256 * 4;                 // 18.9 MB (whole batch)
    size_t rem = (ws_size > off) ? ws_size - off : 0;

    float* u;
    char* xc2base;
    int Bc;
    if (rem >= xc2_full) {
        // Single-pass: u ALIASES the xc2 region (xc2 dead after last gemm;
        // u first written by prim2u which runs after all gemms).
        xc2base = wsb + off;
        u = (float*)xc2base;
        Bc = B;
    } else {
        // Fallback: separate u, chunked xc2 (balanced, multiple of 16).
        u = (float*)(wsb + off);
        off += usz;
        rem = (ws_size > off) ? ws_size - off : 0;
        xc2base = wsb + off;
        long Bcmax = (long)(rem / 409600);
        if (Bcmax < 1) Bcmax = 1;
        if (Bcmax > B) Bcmax = B;
        int nch = (int)((B + Bcmax - 1) / Bcmax);
        Bc = (B + nch - 1) / nch;
        Bc = (Bc + 15) & ~15;
        if (Bc > Bcmax) Bc = (int)(Bcmax & ~15L);
        if (Bc < 1) Bc = (int)Bcmax;
    }

    hipMemsetAsync(prim, 0, (size_t)Mg * 256 * 4, stream);
    prep_kernel<<<5184, 256, 0, stream>>>(conv1_w, prim_w, wT1, wpk);

    for (int b0 = 0; b0 < B; b0 += Bc) {
        int bc = (B - b0 < Bc) ? (B - b0) : Bc;
        conv1_kernel<<<bc, 256, 0, stream>>>(images, wT1, conv1_b, xc2base, b0);
        int M = bc * 36;
        int Mtiles = (M + 191) / 192;
        gemm_kernel<<<Mtiles * 8, 512, 0, stream>>>(xc2base, wpk, prim, M, Mtiles, b0 * 36);
    }
    prim2u_kernel<<<(Mg + 63) / 64, 256, 0, stream>>>(prim, prim_b, u, Mg);
    dim3 rg((B + 1) / 2, 10);
    routing_kernel<<<rg, 512, 0, stream>>>(u, W, out, B);
}

// Round 15
// 1017.671 us; speedup vs baseline: 1.1689x; 1.1689x over previous
//
#include <hip/hip_runtime.h>
#include <hip/hip_bf16.h>
#include <cstddef>
#include <cstdint>

typedef __attribute__((ext_vector_type(8))) short v8s;     // 8 bf16 (4 VGPR)
typedef __attribute__((ext_vector_type(16))) float v16f;   // MFMA 32x32 acc

#define GLDS(SRC, DST) __builtin_amdgcn_global_load_lds( \
    (const __attribute__((address_space(1))) void*)(SRC), \
    (__attribute__((address_space(3))) void*)(DST), 16, 0, 0)

// RNE fp32 -> bf16 split: x ~= hi + lo, |x - hi - lo| <~ 2^-18 |x|
__device__ __forceinline__ void bf16split(float x, unsigned short& h, unsigned short& l) {
    union { float f; unsigned u; } a; a.f = x;
    unsigned r = a.u + 0x7fff + ((a.u >> 16) & 1);
    h = (unsigned short)(r >> 16);
    union { unsigned u; float f; } hb; hb.u = (unsigned)h << 16;
    union { float f; unsigned u; } b; b.f = x - hb.f;
    unsigned r2 = b.u + 0x7fff + ((b.u >> 16) & 1);
    l = (unsigned short)(r2 >> 16);
}

// ---------------------------------------------------------------------------
// prep (R8 form, measured-best): wT1[k*256+oc] = conv1_w[oc*81+k]
// wpk: 648 slabs (g 0..7, k 0..80) of 32 KB = 64 rows x 512 B, GLDS-linear
// pre-swizzled: byte D: R=D>>9, v=(D&511)^((R&31)<<4), h=v>>7, pl=(v>>6)&1,
// icb=v&63 -> ch=64h+R, ic=g*32+icb/2, plane pl of split(pw[ch][ic][k]).
// ---------------------------------------------------------------------------
__global__ __launch_bounds__(256) void prep_kernel(
    const float* __restrict__ cw, const float* __restrict__ pw,
    float* __restrict__ wT1, char* __restrict__ wpk)
{
    int idx = blockIdx.x * 256 + threadIdx.x;
    if (idx < 81 * 256) {
        int k = idx >> 8, oc = idx & 255;
        wT1[idx] = cw[oc * 81 + k];
    }
    int Q = idx & 2047;
    int slab = idx >> 11;                 // 0..647
    int D = Q << 4;
    int R = D >> 9;                       // 0..63
    int v = (D & 511) ^ ((R & 31) << 4);
    int h = v >> 7, pl = (v >> 6) & 1, icb = v & 63;
    int ch = h * 64 + R;
    int g = slab / 81, k = slab - g * 81;
    int ic0 = g * 32 + (icb >> 1);
    const float* src = pw + ((size_t)ch * 256 + ic0) * 81 + k;
    v8s ov;
#pragma unroll
    for (int j = 0; j < 8; ++j) {
        unsigned short hh, ll; bf16split(src[(size_t)j * 81], hh, ll);
        ov[j] = (short)(pl ? ll : hh);
    }
    *(v8s*)(wpk + (size_t)slab * 32768 + D) = ov;
}

// ---------------------------------------------------------------------------
// conv1 (register-tiled): [B,1,28,28] -> xc2 rows of 1024 B [hi 256][lo 256]
// ---------------------------------------------------------------------------
__global__ __launch_bounds__(256) void conv1_kernel(
    const float* __restrict__ img,   // [B][784]
    const float* __restrict__ wT1,   // [81][256]
    const float* __restrict__ bias,  // [256]
    char* __restrict__ xc2,          // [bc][400][1024 B]
    int b0)
{
    const int bl = blockIdx.x;
    const int oc = threadIdx.x;
    __shared__ __align__(16) float im[784];
    const float* ib = img + (size_t)(b0 + bl) * 784;
    for (int e = oc; e < 784; e += 256) im[e] = ib[e];
    float w[81];
#pragma unroll
    for (int k = 0; k < 81; ++k) w[k] = wT1[k * 256 + oc];
    float bv = bias[oc];
    __syncthreads();
    char* ob = xc2 + (size_t)bl * 409600;
    for (int oy = 0; oy < 20; ++oy) {
        float a[20];
#pragma unroll
        for (int ox = 0; ox < 20; ++ox) a[ox] = bv;
        for (int ky = 0; ky < 9; ++ky) {
            const float* rp = &im[(oy + ky) * 28];
            float r[28];
#pragma unroll
            for (int q = 0; q < 7; ++q) {
                float4 v4 = *(const float4*)(rp + q * 4);
                r[q * 4] = v4.x; r[q * 4 + 1] = v4.y;
                r[q * 4 + 2] = v4.z; r[q * 4 + 3] = v4.w;
            }
#pragma unroll
            for (int kx = 0; kx < 9; ++kx) {
                float wv = w[ky * 9 + kx];
#pragma unroll
                for (int ox = 0; ox < 20; ++ox)
                    a[ox] = fmaf(wv, r[ox + kx], a[ox]);
            }
        }
#pragma unroll
        for (int ox = 0; ox < 20; ++ox) {
            float av = fmaxf(a[ox], 0.f);
            unsigned short h, l; bf16split(av, h, l);
            char* rp2 = ob + (size_t)(oy * 20 + ox) * 1024;
            *(unsigned short*)(rp2 + oc * 2) = h;
            *(unsigned short*)(rp2 + 512 + oc * 2) = l;
        }
    }
}

// ---------------------------------------------------------------------------
// primary conv implicit GEMM (R13 engine verbatim, measured-best), split-bf16
// (3 products), split-K x8, g-SLOWEST grid. BM=192 x BN=256, 8 waves
// (wm=w&1 over 96 m-rows, wn=w>>1 over 64 ch), wave-tile 96x64.
// A LDS: 48 rows x 512 B (m = 48h+R); B: 64 rows x 512 B (ch = 64h+R);
// XOR over 32 slots. Double-buffered 112 KB, ONE __syncthreads per step.
// Epilogue: atomicAdd into the single whole-batch prim plane at global m.
// ---------------------------------------------------------------------------
__global__ __launch_bounds__(512, 1) void gemm_kernel(
    const char* __restrict__ xc2,   // [bc][400][1024 B]
    const char* __restrict__ wpk,   // [648 slabs][32 KB]
    float* __restrict__ prim,       // [B*36][256], pre-zeroed
    int M, int Mtiles, int gm0)     // M = bc*36 local; gm0 = b0*36
{
    __shared__ __align__(128) char As[2][24576];
    __shared__ __align__(128) char Bs[2][32768];
    const int tid = threadIdx.x;
    const int w = tid >> 6, lane = tid & 63;
    const int wm = w & 1, wn = w >> 1;
    const int col = lane & 31, kg = lane >> 5;
    const int id = blockIdx.x;
    const int g = id / Mtiles;
    const int tile = id - g * Mtiles;
    const int m0 = tile * 192;

    // A-gather per-lane constants (3 GLDS of 1 KB per wave)
    int pbase[3], asrc[3];
#pragma unroll
    for (int i = 0; i < 3; ++i) {
        int d = (w * 3 + i) * 1024 + lane * 16;    // 0..24575
        int R = d >> 9;                            // 0..47
        int v = (d & 511) ^ ((R & 31) << 4);
        int h = v >> 7, pl = (v >> 6) & 1, icb = v & 63;
        int m = m0 + 48 * h + R; if (m >= M) m = M - 1;
        int b = m / 36, s6 = m - b * 36;
        pbase[i] = b * 400 + (s6 / 6) * 40 + (s6 % 6) * 2;
        asrc[i] = pl * 512 + g * 64 + icb;
    }
    // A fragment-read constants: m = wm*96 + fm*32 + col
    int Abase[3], Ahof[3], Axor[3];
#pragma unroll
    for (int fm = 0; fm < 3; ++fm) {
        int m = wm * 96 + fm * 32 + col;
        int h = m / 48, R = m - h * 48;
        Abase[fm] = R * 512;
        Ahof[fm] = h * 128;
        Axor[fm] = (R & 31) << 4;
    }
    const char* wg = wpk + (size_t)g * 81 * 32768;

    v16f acc[3][2];
#pragma unroll
    for (int i = 0; i < 3; ++i)
#pragma unroll
        for (int j = 0; j < 2; ++j)
#pragma unroll
            for (int e = 0; e < 16; ++e) acc[i][j][e] = 0.f;

    // stage step kk into buffer nb (7 GLDS per thread: 3 A + 4 B)
    auto stage = [&](int nb, int kk) {
        const int koff = (kk / 9) * 20 + (kk % 9);
#pragma unroll
        for (int i = 0; i < 3; ++i)
            GLDS(xc2 + (size_t)(pbase[i] + koff) * 1024 + asrc[i],
                 &As[nb][(w * 3 + i) * 1024]);
        const char* bs = wg + (size_t)kk * 32768;
#pragma unroll
        for (int i = 0; i < 4; ++i)
            GLDS(bs + (w * 4 + i) * 1024 + lane * 16,
                 &Bs[nb][(w * 4 + i) * 1024]);
    };

    stage(0, 0);
    __syncthreads();

    const int xr = col << 4;
    for (int k = 0; k < 81; ++k) {
        const int cur = k & 1;
        if (k < 80) stage(cur ^ 1, k + 1);
        const char* Ab = &As[cur][0];
        const char* Bb = &Bs[cur][0];
#pragma unroll
        for (int s = 0; s < 2; ++s) {
            const int vb = s * 32 + kg * 16;
            v8s Ah[3], Al[3], Bh[2], Bl[2];
#pragma unroll
            for (int fm = 0; fm < 3; ++fm) {
                const char* ap = Ab + Abase[fm];
                Ah[fm] = *(const v8s*)(ap + ((Ahof[fm] + vb) ^ Axor[fm]));
                Al[fm] = *(const v8s*)(ap + ((Ahof[fm] + 64 + vb) ^ Axor[fm]));
            }
#pragma unroll
            for (int fn = 0; fn < 2; ++fn) {
                const char* bp = Bb + (fn * 32 + col) * 512;
                Bh[fn] = *(const v8s*)(bp + ((wn * 128 + vb) ^ xr));
                Bl[fn] = *(const v8s*)(bp + ((wn * 128 + 64 + vb) ^ xr));
            }
            __builtin_amdgcn_s_setprio(1);
#pragma unroll
            for (int fn = 0; fn < 2; ++fn)
#pragma unroll
                for (int fm = 0; fm < 3; ++fm) {
                    acc[fm][fn] = __builtin_amdgcn_mfma_f32_32x32x16_bf16(Al[fm], Bh[fn], acc[fm][fn], 0, 0, 0);
                    acc[fm][fn] = __builtin_amdgcn_mfma_f32_32x32x16_bf16(Ah[fm], Bl[fn], acc[fm][fn], 0, 0, 0);
                    acc[fm][fn] = __builtin_amdgcn_mfma_f32_32x32x16_bf16(Ah[fm], Bh[fn], acc[fm][fn], 0, 0, 0);
                }
            __builtin_amdgcn_s_setprio(0);
        }
        if (k < 80) __syncthreads();
    }

    // epilogue: atomic accumulate into the single prim plane (global m)
    float* pg = prim + (size_t)gm0 * 256;
#pragma unroll
    for (int fm = 0; fm < 3; ++fm)
#pragma unroll
        for (int fn = 0; fn < 2; ++fn) {
            int ch = wn * 64 + fn * 32 + col;
#pragma unroll
            for (int rg = 0; rg < 16; ++rg) {
                int row = (rg & 3) + 8 * (rg >> 2) + 4 * kg;
                int m = m0 + wm * 96 + fm * 32 + row;
                if (m < M) atomicAdd(&pg[(size_t)m * 256 + ch], acc[fm][fn][rg]);
            }
        }
}

// ---------------------------------------------------------------------------
// prim (1 plane, full batch) -> +bias -> regroup -> squash -> u [B][1152][8]
// ---------------------------------------------------------------------------
__global__ __launch_bounds__(256) void prim2u_kernel(
    const float* __restrict__ prim, const float* __restrict__ pb,
    float* __restrict__ u, int M)
{
    __shared__ float p[64 * 257];    // 65.8 KB
    __shared__ float bsh[256];
    const int tid = threadIdx.x;
    const int rows0 = blockIdx.x * 64;
    bsh[tid] = pb[tid];
#pragma unroll
    for (int j = 0; j < 16; ++j) {
        int e4 = j * 256 + tid;
        int row = e4 >> 6, c4 = (e4 & 63) << 2;
        int rr = rows0 + row; if (rr >= M) rr = M - 1;
        float4 a = *(const float4*)(prim + (size_t)rr * 256 + c4);
        float* pp = &p[row * 257 + c4];
        pp[0] = a.x; pp[1] = a.y; pp[2] = a.z; pp[3] = a.w;
    }
    __syncthreads();
#pragma unroll
    for (int j = 0; j < 8; ++j) {
        int idx = j * 256 + tid;          // 64 rows x 32 cc
        int row = idx & 63, cc = idx >> 6;
        int m = rows0 + row;
        if (m >= M) continue;
        int b = m / 36, s = m - b * 36;
        float p8[8]; float sn = 0.f;
#pragma unroll
        for (int d = 0; d < 8; ++d) {
            float v = p[row * 257 + d * 32 + cc] + bsh[d * 32 + cc];
            p8[d] = v; sn += v * v;
        }
        float fac = sqrtf(sn) / (1.0f + sn);
        float4 o0, o1;
        o0.x = fac * p8[0]; o0.y = fac * p8[1]; o0.z = fac * p8[2]; o0.w = fac * p8[3];
        o1.x = fac * p8[4]; o1.y = fac * p8[5]; o1.z = fac * p8[6]; o1.w = fac * p8[7];
        float* up = u + ((size_t)b * 1152 + cc * 36 + s) * 8;
        *(float4*)up = o0;
        *(float4*)(up + 4) = o1;
    }
}

// ---------------------------------------------------------------------------
// routing: c-MAJOR 1-D grid (id = c*npairs + pair). npairs == 256 == number
// of co-resident blocks (1/CU at 157 KB LDS), so all resident blocks read
// the SAME W[c] (590 KB) -> W served from each XCD's L2 after ~8 compulsory
// misses, instead of 1.5 GB from L3. Block body identical to R13 (R8 form).
// ---------------------------------------------------------------------------
__global__ __launch_bounds__(512) void routing_kernel(
    const float* __restrict__ u,   // [B][1152][8]
    const float* __restrict__ W,   // [10][1152][8][16]
    float* __restrict__ out,       // [B][10][16]
    int B, int npairs)
{
    const int id = blockIdx.x;
    const int c = id / npairs;
    const int pair = id - c * npairs;
    const int b0 = pair * 2;
    const int tid = threadIdx.x;
    __shared__ float uht[2][16][1152];    // 147456 B
    __shared__ float bijs[2][1152];       // 9216 B
    __shared__ float red[2][4 * 17];
    __shared__ float sred[2][17];
    __shared__ float mred[2][4];

    const float* __restrict__ Wc = W + (size_t)c * (1152 * 128);
    const int b1 = (b0 + 1 < B) ? b0 + 1 : b0;
    const float* __restrict__ ub0 = u + (size_t)b0 * 9216;
    const float* __restrict__ ub1 = u + (size_t)b1 * 9216;

    for (int n = tid; n < 1152; n += 512) {
        const float4* p0 = (const float4*)(ub0 + n * 8);
        const float4* p1 = (const float4*)(ub1 + n * 8);
        float4 a0 = p0[0], a1 = p0[1], c0 = p1[0], c1 = p1[1];
        float uu0[8] = {a0.x, a0.y, a0.z, a0.w, a1.x, a1.y, a1.z, a1.w};
        float uu1[8] = {c0.x, c0.y, c0.z, c0.w, c1.x, c1.y, c1.z, c1.w};
        float acc0[16], acc1[16];
#pragma unroll
        for (int o = 0; o < 16; ++o) { acc0[o] = 0.f; acc1[o] = 0.f; }
        const float* wn = Wc + n * 128;
#pragma unroll
        for (int i = 0; i < 8; ++i)
#pragma unroll
            for (int o = 0; o < 16; ++o) {
                float wv = wn[i * 16 + o];
                acc0[o] = fmaf(uu0[i], wv, acc0[o]);
                acc1[o] = fmaf(uu1[i], wv, acc1[o]);
            }
#pragma unroll
        for (int o = 0; o < 16; ++o) { uht[0][o][n] = acc0[o]; uht[1][o][n] = acc1[o]; }
        bijs[0][n] = 0.f; bijs[1][n] = 0.f;
    }
    __syncthreads();

    const int img = tid >> 8, t = tid & 255;
    const int wid = t >> 6, lane = t & 63;
    const float* __restrict__ UHT = &uht[img][0][0];
    float* __restrict__ bij = bijs[img];
    float* __restrict__ redi = red[img];
    float* __restrict__ sredi = sred[img];
    float* __restrict__ mredi = mred[img];

    float fac = 0.f, inv = 0.f;
    for (int it = 0; it < 3; ++it) {
        float m = -3.4e38f;
        for (int n = t; n < 1152; n += 256) m = fmaxf(m, bij[n]);
#pragma unroll
        for (int off = 32; off > 0; off >>= 1) m = fmaxf(m, __shfl_down(m, off));
        if (lane == 0) mredi[wid] = m;
        __syncthreads();
        float M = fmaxf(fmaxf(mredi[0], mredi[1]), fmaxf(mredi[2], mredi[3]));
        float se = 0.f;
        float sp[16];
#pragma unroll
        for (int o = 0; o < 16; ++o) sp[o] = 0.f;
        for (int n = t; n < 1152; n += 256) {
            float e = expf(bij[n] - M);
            se += e;
#pragma unroll
            for (int o = 0; o < 16; ++o) sp[o] = fmaf(e, UHT[o * 1152 + n], sp[o]);
        }
#pragma unroll
        for (int o = 0; o < 16; ++o)
#pragma unroll
            for (int off = 32; off > 0; off >>= 1) sp[o] += __shfl_down(sp[o], off);
#pragma unroll
        for (int off = 32; off > 0; off >>= 1) se += __shfl_down(se, off);
        if (lane == 0) {
#pragma unroll
            for (int o = 0; o < 16; ++o) redi[wid * 17 + o] = sp[o];
            redi[wid * 17 + 16] = se;
        }
        __syncthreads();
        if (t < 17)
            sredi[t] = redi[t] + redi[17 + t] + redi[34 + t] + redi[51 + t];
        __syncthreads();
        inv = 1.0f / sredi[16];
        float sn = 0.f;
        float sj[16];
#pragma unroll
        for (int o = 0; o < 16; ++o) { sj[o] = sredi[o] * inv; sn = fmaf(sj[o], sj[o], sn); }
        fac = sqrtf(sn) / (1.0f + sn);
        if (it < 2) {
            float v[16];
#pragma unroll
            for (int o = 0; o < 16; ++o) v[o] = fac * sj[o];
            for (int n = t; n < 1152; n += 256) {
                float a = 0.f;
#pragma unroll
                for (int o = 0; o < 16; ++o) a = fmaf(UHT[o * 1152 + n], v[o], a);
                bij[n] += a;
            }
        }
        __syncthreads();
    }
    if (t < 16 && b0 + img < B)
        out[((size_t)(b0 + img) * 10 + c) * 16 + t] = fac * (sredi[t] * inv);
}

// ---------------------------------------------------------------------------
extern "C" void kernel_launch(void* const* d_in, const int* in_sizes, int n_in,
                              void* d_out, int out_size, void* d_ws, size_t ws_size,
                              hipStream_t stream) {
    const float* images  = (const float*)d_in[0];
    const float* conv1_w = (const float*)d_in[1];
    const float* conv1_b = (const float*)d_in[2];
    const float* prim_w  = (const float*)d_in[3];
    const float* prim_b  = (const float*)d_in[4];
    const float* W       = (const float*)d_in[5];
    float* out = (float*)d_out;

    const int B = in_sizes[0] / 784;
    const int Mg = B * 36;
    const size_t usz = (size_t)B * 1152 * 8 * 4;      // 18.9 MB @ B=512
    const size_t xc2_full = (size_t)B * 409600;       // 209.7 MB @ B=512

    char* wsb = (char*)d_ws;
    size_t off = 0;
    float* wT1 = (float*)(wsb + off);
    off += 81 * 256 * 4;
    off = (off + 1023) & ~(size_t)1023;
    char* wpk = wsb + off;
    off += (size_t)648 * 32768;                  // 21.2 MB
    float* prim = (float*)(wsb + off);
    off += (size_t)Mg * 256 * 4;                 // 18.9 MB (whole batch)
    size_t rem = (ws_size > off) ? ws_size - off : 0;

    float* u;
    char* xc2base;
    int Bc;
    if (rem >= xc2_full) {
        // Single-pass: u ALIASES the xc2 region (xc2 dead after last gemm;
        // u first written by prim2u which runs after all gemms).
        xc2base = wsb + off;
        u = (float*)xc2base;
        Bc = B;
    } else {
        // Fallback: separate u, chunked xc2 (balanced, multiple of 16).
        u = (float*)(wsb + off);
        off += usz;
        rem = (ws_size > off) ? ws_size - off : 0;
        xc2base = wsb + off;
        long Bcmax = (long)(rem / 409600);
        if (Bcmax < 1) Bcmax = 1;
        if (Bcmax > B) Bcmax = B;
        int nch = (int)((B + Bcmax - 1) / Bcmax);
        Bc = (B + nch - 1) / nch;
        Bc = (Bc + 15) & ~15;
        if (Bc > Bcmax) Bc = (int)(Bcmax & ~15L);
        if (Bc < 1) Bc = (int)Bcmax;
    }

    hipMemsetAsync(prim, 0, (size_t)Mg * 256 * 4, stream);
    prep_kernel<<<5184, 256, 0, stream>>>(conv1_w, prim_w, wT1, wpk);

    for (int b0 = 0; b0 < B; b0 += Bc) {
        int bc = (B - b0 < Bc) ? (B - b0) : Bc;
        conv1_kernel<<<bc, 256, 0, stream>>>(images, wT1, conv1_b, xc2base, b0);
        int M = bc * 36;
        int Mtiles = (M + 191) / 192;
        gemm_kernel<<<Mtiles * 8, 512, 0, stream>>>(xc2base, wpk, prim, M, Mtiles, b0 * 36);
    }
    prim2u_kernel<<<(Mg + 63) / 64, 256, 0, stream>>>(prim, prim_b, u, Mg);
    int npairs = (B + 1) / 2;
    routing_kernel<<<npairs * 10, 512, 0, stream>>>(u, W, out, B, npairs);
}

// Round 16
// 977.210 us; speedup vs baseline: 1.2173x; 1.0414x over previous
//
#include <hip/hip_runtime.h>
#include <hip/hip_bf16.h>
#include <cstddef>
#include <cstdint>

typedef __attribute__((ext_vector_type(8))) short v8s;     // 8 bf16 (4 VGPR)
typedef __attribute__((ext_vector_type(16))) float v16f;   // MFMA 32x32 acc

#define GLDS(SRC, DST) __builtin_amdgcn_global_load_lds( \
    (const __attribute__((address_space(1))) void*)(SRC), \
    (__attribute__((address_space(3))) void*)(DST), 16, 0, 0)

#define WAIT_VM4() asm volatile("s_waitcnt vmcnt(4)" ::: "memory")
#define WAIT_VM0() asm volatile("s_waitcnt vmcnt(0)" ::: "memory")
#define SCHED0()   __builtin_amdgcn_sched_barrier(0)

// RNE fp32 -> bf16 split: x ~= hi + lo, |x - hi - lo| <~ 2^-18 |x|
__device__ __forceinline__ void bf16split(float x, unsigned short& h, unsigned short& l) {
    union { float f; unsigned u; } a; a.f = x;
    unsigned r = a.u + 0x7fff + ((a.u >> 16) & 1);
    h = (unsigned short)(r >> 16);
    union { unsigned u; float f; } hb; hb.u = (unsigned)h << 16;
    union { float f; unsigned u; } b; b.f = x - hb.f;
    unsigned r2 = b.u + 0x7fff + ((b.u >> 16) & 1);
    l = (unsigned short)(r2 >> 16);
}

// ---------------------------------------------------------------------------
// prep (R8 form, measured-best): wT1[k*256+oc] = conv1_w[oc*81+k]
// wpk: 648 slabs (g 0..7, k 0..80) of 32 KB = 64 rows x 512 B, GLDS-linear
// pre-swizzled: byte D: R=D>>9, v=(D&511)^((R&31)<<4), h=v>>7, pl=(v>>6)&1,
// icb=v&63 -> ch=64h+R, ic=g*32+icb/2, plane pl of split(pw[ch][ic][k]).
// ---------------------------------------------------------------------------
__global__ __launch_bounds__(256) void prep_kernel(
    const float* __restrict__ cw, const float* __restrict__ pw,
    float* __restrict__ wT1, char* __restrict__ wpk)
{
    int idx = blockIdx.x * 256 + threadIdx.x;
    if (idx < 81 * 256) {
        int k = idx >> 8, oc = idx & 255;
        wT1[idx] = cw[oc * 81 + k];
    }
    int Q = idx & 2047;
    int slab = idx >> 11;                 // 0..647
    int D = Q << 4;
    int R = D >> 9;                       // 0..63
    int v = (D & 511) ^ ((R & 31) << 4);
    int h = v >> 7, pl = (v >> 6) & 1, icb = v & 63;
    int ch = h * 64 + R;
    int g = slab / 81, k = slab - g * 81;
    int ic0 = g * 32 + (icb >> 1);
    const float* src = pw + ((size_t)ch * 256 + ic0) * 81 + k;
    v8s ov;
#pragma unroll
    for (int j = 0; j < 8; ++j) {
        unsigned short hh, ll; bf16split(src[(size_t)j * 81], hh, ll);
        ov[j] = (short)(pl ? ll : hh);
    }
    *(v8s*)(wpk + (size_t)slab * 32768 + D) = ov;
}

// ---------------------------------------------------------------------------
// conv1 (register-tiled): [B,1,28,28] -> xc2 rows of 1024 B [hi 256][lo 256]
// ---------------------------------------------------------------------------
__global__ __launch_bounds__(256) void conv1_kernel(
    const float* __restrict__ img,   // [B][784]
    const float* __restrict__ wT1,   // [81][256]
    const float* __restrict__ bias,  // [256]
    char* __restrict__ xc2,          // [bc][400][1024 B]
    int b0)
{
    const int bl = blockIdx.x;
    const int oc = threadIdx.x;
    __shared__ __align__(16) float im[784];
    const float* ib = img + (size_t)(b0 + bl) * 784;
    for (int e = oc; e < 784; e += 256) im[e] = ib[e];
    float w[81];
#pragma unroll
    for (int k = 0; k < 81; ++k) w[k] = wT1[k * 256 + oc];
    float bv = bias[oc];
    __syncthreads();
    char* ob = xc2 + (size_t)bl * 409600;
    for (int oy = 0; oy < 20; ++oy) {
        float a[20];
#pragma unroll
        for (int ox = 0; ox < 20; ++ox) a[ox] = bv;
        for (int ky = 0; ky < 9; ++ky) {
            const float* rp = &im[(oy + ky) * 28];
            float r[28];
#pragma unroll
            for (int q = 0; q < 7; ++q) {
                float4 v4 = *(const float4*)(rp + q * 4);
                r[q * 4] = v4.x; r[q * 4 + 1] = v4.y;
                r[q * 4 + 2] = v4.z; r[q * 4 + 3] = v4.w;
            }
#pragma unroll
            for (int kx = 0; kx < 9; ++kx) {
                float wv = w[ky * 9 + kx];
#pragma unroll
                for (int ox = 0; ox < 20; ++ox)
                    a[ox] = fmaf(wv, r[ox + kx], a[ox]);
            }
        }
#pragma unroll
        for (int ox = 0; ox < 20; ++ox) {
            float av = fmaxf(a[ox], 0.f);
            unsigned short h, l; bf16split(av, h, l);
            char* rp2 = ob + (size_t)(oy * 20 + ox) * 1024;
            *(unsigned short*)(rp2 + oc * 2) = h;
            *(unsigned short*)(rp2 + 512 + oc * 2) = l;
        }
    }
}

// ---------------------------------------------------------------------------
// primary conv implicit GEMM, split-bf16 (3 products), split-K x8, g-SLOWEST
// grid. BM=192 x BN=256, 8 waves, wave-tile 96x64. T3+T4 COMBO:
// A double-buffered (2x24 KB) + B TRIPLE-buffered (3x32 KB) = 144 KB.
// Step k issues A(k+1) (phases 0-1) and B(k+2) (phases 1-3); step-end wait
// is vmcnt(4): exactly B(k+2)'s 4 loads stay in flight across the barrier.
// 4 phases/step: {ds_read frags ; 1-2 GLDS ; s_barrier ; setprio(1) ;
// 9 MFMA ; setprio(0) ; s_barrier}. Every ds_read is consumed by an MFMA
// before the next barrier (lgkmcnt naturally drained); buffers k/k+1/k+2
// distinct mod 2 (A) and mod 3 (B).
// ---------------------------------------------------------------------------
__global__ __launch_bounds__(512, 1) void gemm_kernel(
    const char* __restrict__ xc2,   // [bc][400][1024 B]
    const char* __restrict__ wpk,   // [648 slabs][32 KB]
    float* __restrict__ prim,       // [B*36][256], pre-zeroed
    int M, int Mtiles, int gm0)     // M = bc*36 local; gm0 = b0*36
{
    __shared__ __align__(128) char As[2][24576];
    __shared__ __align__(128) char Bs[3][32768];
    const int tid = threadIdx.x;
    const int w = tid >> 6, lane = tid & 63;
    const int wm = w & 1, wn = w >> 1;
    const int col = lane & 31, kg = lane >> 5;
    const int id = blockIdx.x;
    const int g = id / Mtiles;
    const int tile = id - g * Mtiles;
    const int m0 = tile * 192;

    // A-gather per-lane constants (3 GLDS of 1 KB per wave)
    int pbase[3], asrc[3];
#pragma unroll
    for (int i = 0; i < 3; ++i) {
        int d = (w * 3 + i) * 1024 + lane * 16;    // 0..24575
        int R = d >> 9;                            // 0..47
        int v = (d & 511) ^ ((R & 31) << 4);
        int h = v >> 7, pl = (v >> 6) & 1, icb = v & 63;
        int m = m0 + 48 * h + R; if (m >= M) m = M - 1;
        int b = m / 36, s6 = m - b * 36;
        pbase[i] = b * 400 + (s6 / 6) * 40 + (s6 % 6) * 2;
        asrc[i] = pl * 512 + g * 64 + icb;
    }
    // A fragment-read constants: m = wm*96 + fm*32 + col
    int Abase[3], Ahof[3], Axor[3];
#pragma unroll
    for (int fm = 0; fm < 3; ++fm) {
        int m = wm * 96 + fm * 32 + col;
        int h = m / 48, R = m - h * 48;
        Abase[fm] = R * 512;
        Ahof[fm] = h * 128;
        Axor[fm] = (R & 31) << 4;
    }
    const char* wg = wpk + (size_t)g * 81 * 32768;

    v16f acc[3][2];
#pragma unroll
    for (int i = 0; i < 3; ++i)
#pragma unroll
        for (int j = 0; j < 2; ++j)
#pragma unroll
            for (int e = 0; e < 16; ++e) acc[i][j][e] = 0.f;

    auto gldsA = [&](int nb, int kk, int i) {
        const int koff = (kk / 9) * 20 + (kk % 9);
        GLDS(xc2 + (size_t)(pbase[i] + koff) * 1024 + asrc[i],
             &As[nb][(w * 3 + i) * 1024]);
    };
    auto gldsB = [&](int nb, int kk, int i) {
        GLDS(wg + (size_t)kk * 32768 + (w * 4 + i) * 1024 + lane * 16,
             &Bs[nb][(w * 4 + i) * 1024]);
    };

    // prologue: A(0), B(0) needed for step 0; B(1) stays in flight
#pragma unroll
    for (int i = 0; i < 3; ++i) gldsA(0, 0, i);
#pragma unroll
    for (int i = 0; i < 4; ++i) gldsB(0, 0, i);
#pragma unroll
    for (int i = 0; i < 4; ++i) gldsB(1, 1, i);
    WAIT_VM4(); SCHED0();
    __builtin_amdgcn_s_barrier(); SCHED0();

    const int xr = col << 4;
    v8s Ah[3], Al[3];
    for (int k = 0; k < 81; ++k) {
        const char* Ab = &As[k & 1][0];
        const char* Bb = &Bs[k % 3][0];
        const int nA = (k + 1) & 1, nB = (k + 2) % 3;
        const bool stA = (k < 80), stB = (k < 79);

#pragma unroll
        for (int p = 0; p < 4; ++p) {
            const int s = p >> 1, fn = p & 1;
            const int vb = s * 32 + kg * 16;
            // phase fragment reads (A persists across fn=0 -> fn=1)
            if (fn == 0) {
#pragma unroll
                for (int fm = 0; fm < 3; ++fm) {
                    const char* ap = Ab + Abase[fm];
                    Ah[fm] = *(const v8s*)(ap + ((Ahof[fm] + vb) ^ Axor[fm]));
                    Al[fm] = *(const v8s*)(ap + ((Ahof[fm] + 64 + vb) ^ Axor[fm]));
                }
            }
            const char* bp = Bb + (fn * 32 + col) * 512;
            v8s Bh = *(const v8s*)(bp + ((wn * 128 + vb) ^ xr));
            v8s Bl = *(const v8s*)(bp + ((wn * 128 + 64 + vb) ^ xr));
            // stage portion (A(k+1) first, B(k+2) last -> vmcnt(4) counts B)
            if (p == 0) { if (stA) { gldsA(nA, k + 1, 0); gldsA(nA, k + 1, 1); } }
            else if (p == 1) { if (stA) gldsA(nA, k + 1, 2); if (stB) gldsB(nB, k + 2, 0); }
            else if (p == 2) { if (stB) { gldsB(nB, k + 2, 1); gldsB(nB, k + 2, 2); } }
            else { if (stB) gldsB(nB, k + 2, 3); }

            __builtin_amdgcn_s_barrier();
            SCHED0();
            __builtin_amdgcn_s_setprio(1);
#pragma unroll
            for (int fm = 0; fm < 3; ++fm) {
                acc[fm][fn] = __builtin_amdgcn_mfma_f32_32x32x16_bf16(Al[fm], Bh, acc[fm][fn], 0, 0, 0);
                acc[fm][fn] = __builtin_amdgcn_mfma_f32_32x32x16_bf16(Ah[fm], Bl, acc[fm][fn], 0, 0, 0);
                acc[fm][fn] = __builtin_amdgcn_mfma_f32_32x32x16_bf16(Ah[fm], Bh, acc[fm][fn], 0, 0, 0);
            }
            __builtin_amdgcn_s_setprio(0);
            SCHED0();
            if (p < 3) {
                __builtin_amdgcn_s_barrier();
            } else if (stA) {
                if (stB) { WAIT_VM4(); } else { WAIT_VM0(); }
                SCHED0();
                __builtin_amdgcn_s_barrier(); SCHED0();
            }
        }
    }

    // epilogue: atomic accumulate into the single prim plane (global m)
    float* pg = prim + (size_t)gm0 * 256;
#pragma unroll
    for (int fm = 0; fm < 3; ++fm)
#pragma unroll
        for (int fn = 0; fn < 2; ++fn) {
            int ch = wn * 64 + fn * 32 + col;
#pragma unroll
            for (int rg = 0; rg < 16; ++rg) {
                int row = (rg & 3) + 8 * (rg >> 2) + 4 * kg;
                int m = m0 + wm * 96 + fm * 32 + row;
                if (m < M) atomicAdd(&pg[(size_t)m * 256 + ch], acc[fm][fn][rg]);
            }
        }
}

// ---------------------------------------------------------------------------
// prim (1 plane, full batch) -> +bias -> regroup -> squash -> u [B][1152][8]
// ---------------------------------------------------------------------------
__global__ __launch_bounds__(256) void prim2u_kernel(
    const float* __restrict__ prim, const float* __restrict__ pb,
    float* __restrict__ u, int M)
{
    __shared__ float p[64 * 257];    // 65.8 KB
    __shared__ float bsh[256];
    const int tid = threadIdx.x;
    const int rows0 = blockIdx.x * 64;
    bsh[tid] = pb[tid];
#pragma unroll
    for (int j = 0; j < 16; ++j) {
        int e4 = j * 256 + tid;
        int row = e4 >> 6, c4 = (e4 & 63) << 2;
        int rr = rows0 + row; if (rr >= M) rr = M - 1;
        float4 a = *(const float4*)(prim + (size_t)rr * 256 + c4);
        float* pp = &p[row * 257 + c4];
        pp[0] = a.x; pp[1] = a.y; pp[2] = a.z; pp[3] = a.w;
    }
    __syncthreads();
#pragma unroll
    for (int j = 0; j < 8; ++j) {
        int idx = j * 256 + tid;          // 64 rows x 32 cc
        int row = idx & 63, cc = idx >> 6;
        int m = rows0 + row;
        if (m >= M) continue;
        int b = m / 36, s = m - b * 36;
        float p8[8]; float sn = 0.f;
#pragma unroll
        for (int d = 0; d < 8; ++d) {
            float v = p[row * 257 + d * 32 + cc] + bsh[d * 32 + cc];
            p8[d] = v; sn += v * v;
        }
        float fac = sqrtf(sn) / (1.0f + sn);
        float4 o0, o1;
        o0.x = fac * p8[0]; o0.y = fac * p8[1]; o0.z = fac * p8[2]; o0.w = fac * p8[3];
        o1.x = fac * p8[4]; o1.y = fac * p8[5]; o1.z = fac * p8[6]; o1.w = fac * p8[7];
        float* up = u + ((size_t)b * 1152 + cc * 36 + s) * 8;
        *(float4*)up = o0;
        *(float4*)(up + 4) = o1;
    }
}

// ---------------------------------------------------------------------------
// routing: c-major 1-D grid; one block per (b-pair, c), 512 thr, u_hat
// TRANSPOSED in LDS ([16][1152] per image, conflict-free).
// ---------------------------------------------------------------------------
__global__ __launch_bounds__(512) void routing_kernel(
    const float* __restrict__ u,   // [B][1152][8]
    const float* __restrict__ W,   // [10][1152][8][16]
    float* __restrict__ out,       // [B][10][16]
    int B, int npairs)
{
    const int id = blockIdx.x;
    const int c = id / npairs;
    const int pair = id - c * npairs;
    const int b0 = pair * 2;
    const int tid = threadIdx.x;
    __shared__ float uht[2][16][1152];    // 147456 B
    __shared__ float bijs[2][1152];       // 9216 B
    __shared__ float red[2][4 * 17];
    __shared__ float sred[2][17];
    __shared__ float mred[2][4];

    const float* __restrict__ Wc = W + (size_t)c * (1152 * 128);
    const int b1 = (b0 + 1 < B) ? b0 + 1 : b0;
    const float* __restrict__ ub0 = u + (size_t)b0 * 9216;
    const float* __restrict__ ub1 = u + (size_t)b1 * 9216;

    for (int n = tid; n < 1152; n += 512) {
        const float4* p0 = (const float4*)(ub0 + n * 8);
        const float4* p1 = (const float4*)(ub1 + n * 8);
        float4 a0 = p0[0], a1 = p0[1], c0 = p1[0], c1 = p1[1];
        float uu0[8] = {a0.x, a0.y, a0.z, a0.w, a1.x, a1.y, a1.z, a1.w};
        float uu1[8] = {c0.x, c0.y, c0.z, c0.w, c1.x, c1.y, c1.z, c1.w};
        float acc0[16], acc1[16];
#pragma unroll
        for (int o = 0; o < 16; ++o) { acc0[o] = 0.f; acc1[o] = 0.f; }
        const float* wn = Wc + n * 128;
#pragma unroll
        for (int i = 0; i < 8; ++i)
#pragma unroll
            for (int o = 0; o < 16; ++o) {
                float wv = wn[i * 16 + o];
                acc0[o] = fmaf(uu0[i], wv, acc0[o]);
                acc1[o] = fmaf(uu1[i], wv, acc1[o]);
            }
#pragma unroll
        for (int o = 0; o < 16; ++o) { uht[0][o][n] = acc0[o]; uht[1][o][n] = acc1[o]; }
        bijs[0][n] = 0.f; bijs[1][n] = 0.f;
    }
    __syncthreads();

    const int img = tid >> 8, t = tid & 255;
    const int wid = t >> 6, lane = t & 63;
    const float* __restrict__ UHT = &uht[img][0][0];
    float* __restrict__ bij = bijs[img];
    float* __restrict__ redi = red[img];
    float* __restrict__ sredi = sred[img];
    float* __restrict__ mredi = mred[img];

    float fac = 0.f, inv = 0.f;
    for (int it = 0; it < 3; ++it) {
        float m = -3.4e38f;
        for (int n = t; n < 1152; n += 256) m = fmaxf(m, bij[n]);
#pragma unroll
        for (int off = 32; off > 0; off >>= 1) m = fmaxf(m, __shfl_down(m, off));
        if (lane == 0) mredi[wid] = m;
        __syncthreads();
        float M = fmaxf(fmaxf(mredi[0], mredi[1]), fmaxf(mredi[2], mredi[3]));
        float se = 0.f;
        float sp[16];
#pragma unroll
        for (int o = 0; o < 16; ++o) sp[o] = 0.f;
        for (int n = t; n < 1152; n += 256) {
            float e = expf(bij[n] - M);
            se += e;
#pragma unroll
            for (int o = 0; o < 16; ++o) sp[o] = fmaf(e, UHT[o * 1152 + n], sp[o]);
        }
#pragma unroll
        for (int o = 0; o < 16; ++o)
#pragma unroll
            for (int off = 32; off > 0; off >>= 1) sp[o] += __shfl_down(sp[o], off);
#pragma unroll
        for (int off = 32; off > 0; off >>= 1) se += __shfl_down(se, off);
        if (lane == 0) {
#pragma unroll
            for (int o = 0; o < 16; ++o) redi[wid * 17 + o] = sp[o];
            redi[wid * 17 + 16] = se;
        }
        __syncthreads();
        if (t < 17)
            sredi[t] = redi[t] + redi[17 + t] + redi[34 + t] + redi[51 + t];
        __syncthreads();
        inv = 1.0f / sredi[16];
        float sn = 0.f;
        float sj[16];
#pragma unroll
        for (int o = 0; o < 16; ++o) { sj[o] = sredi[o] * inv; sn = fmaf(sj[o], sj[o], sn); }
        fac = sqrtf(sn) / (1.0f + sn);
        if (it < 2) {
            float v[16];
#pragma unroll
            for (int o = 0; o < 16; ++o) v[o] = fac * sj[o];
            for (int n = t; n < 1152; n += 256) {
                float a = 0.f;
#pragma unroll
                for (int o = 0; o < 16; ++o) a = fmaf(UHT[o * 1152 + n], v[o], a);
                bij[n] += a;
            }
        }
        __syncthreads();
    }
    if (t < 16 && b0 + img < B)
        out[((size_t)(b0 + img) * 10 + c) * 16 + t] = fac * (sredi[t] * inv);
}

// ---------------------------------------------------------------------------
extern "C" void kernel_launch(void* const* d_in, const int* in_sizes, int n_in,
                              void* d_out, int out_size, void* d_ws, size_t ws_size,
                              hipStream_t stream) {
    const float* images  = (const float*)d_in[0];
    const float* conv1_w = (const float*)d_in[1];
    const float* conv1_b = (const float*)d_in[2];
    const float* prim_w  = (const float*)d_in[3];
    const float* prim_b  = (const float*)d_in[4];
    const float* W       = (const float*)d_in[5];
    float* out = (float*)d_out;

    const int B = in_sizes[0] / 784;
    const int Mg = B * 36;
    const size_t usz = (size_t)B * 1152 * 8 * 4;      // 18.9 MB @ B=512
    const size_t xc2_full = (size_t)B * 409600;       // 209.7 MB @ B=512

    char* wsb = (char*)d_ws;
    size_t off = 0;
    float* wT1 = (float*)(wsb + off);
    off += 81 * 256 * 4;
    off = (off + 1023) & ~(size_t)1023;
    char* wpk = wsb + off;
    off += (size_t)648 * 32768;                  // 21.2 MB
    float* prim = (float*)(wsb + off);
    off += (size_t)Mg * 256 * 4;                 // 18.9 MB (whole batch)
    size_t rem = (ws_size > off) ? ws_size - off : 0;

    float* u;
    char* xc2base;
    int Bc;
    if (rem >= xc2_full) {
        // Single-pass: u ALIASES the xc2 region (xc2 dead after last gemm;
        // u first written by prim2u which runs after all gemms).
        xc2base = wsb + off;
        u = (float*)xc2base;
        Bc = B;
    } else {
        // Fallback: separate u, chunked xc2 (balanced, multiple of 16).
        u = (float*)(wsb + off);
        off += usz;
        rem = (ws_size > off) ? ws_size - off : 0;
        xc2base = wsb + off;
        long Bcmax = (long)(rem / 409600);
        if (Bcmax < 1) Bcmax = 1;
        if (Bcmax > B) Bcmax = B;
        int nch = (int)((B + Bcmax - 1) / Bcmax);
        Bc = (B + nch - 1) / nch;
        Bc = (Bc + 15) & ~15;
        if (Bc > Bcmax) Bc = (int)(Bcmax & ~15L);
        if (Bc < 1) Bc = (int)Bcmax;
    }

    hipMemsetAsync(prim, 0, (size_t)Mg * 256 * 4, stream);
    prep_kernel<<<5184, 256, 0, stream>>>(conv1_w, prim_w, wT1, wpk);

    for (int b0 = 0; b0 < B; b0 += Bc) {
        int bc = (B - b0 < Bc) ? (B - b0) : Bc;
        conv1_kernel<<<bc, 256, 0, stream>>>(images, wT1, conv1_b, xc2base, b0);
        int M = bc * 36;
        int Mtiles = (M + 191) / 192;
        gemm_kernel<<<Mtiles * 8, 512, 0, stream>>>(xc2base, wpk, prim, M, Mtiles, b0 * 36);
    }
    prim2u_kernel<<<(Mg + 63) / 64, 256, 0, stream>>>(prim, prim_b, u, Mg);
    int npairs = (B + 1) / 2;
    routing_kernel<<<npairs * 10, 512, 0, stream>>>(u, W, out, B, npairs);
}

// Round 17
// 972.776 us; speedup vs baseline: 1.2228x; 1.0046x over previous
//
#include <hip/hip_runtime.h>
#include <hip/hip_bf16.h>
#include <cstddef>
#include <cstdint>

typedef __attribute__((ext_vector_type(8))) short v8s;     // 8 bf16 (4 VGPR)
typedef __attribute__((ext_vector_type(16))) float v16f;   // MFMA 32x32 acc

#define GLDS(SRC, DST) __builtin_amdgcn_global_load_lds( \
    (const __attribute__((address_space(1))) void*)(SRC), \
    (__attribute__((address_space(3))) void*)(DST), 16, 0, 0)

#define WAIT_VM4() asm volatile("s_waitcnt vmcnt(4)" ::: "memory")
#define WAIT_VM0() asm volatile("s_waitcnt vmcnt(0)" ::: "memory")
#define SCHED0()   __builtin_amdgcn_sched_barrier(0)

// RNE fp32 -> bf16 split: x ~= hi + lo, |x - hi - lo| <~ 2^-18 |x|
__device__ __forceinline__ void bf16split(float x, unsigned short& h, unsigned short& l) {
    union { float f; unsigned u; } a; a.f = x;
    unsigned r = a.u + 0x7fff + ((a.u >> 16) & 1);
    h = (unsigned short)(r >> 16);
    union { unsigned u; float f; } hb; hb.u = (unsigned)h << 16;
    union { float f; unsigned u; } b; b.f = x - hb.f;
    unsigned r2 = b.u + 0x7fff + ((b.u >> 16) & 1);
    l = (unsigned short)(r2 >> 16);
}

// ---------------------------------------------------------------------------
// prep (R8 form, measured-best): wT1[k*256+oc] = conv1_w[oc*81+k]
// wpk: 648 slabs (g 0..7, k 0..80) of 32 KB = 64 rows x 512 B, GLDS-linear
// pre-swizzled: byte D: R=D>>9, v=(D&511)^((R&31)<<4), h=v>>7, pl=(v>>6)&1,
// icb=v&63 -> ch=64h+R, ic=g*32+icb/2, plane pl of split(pw[ch][ic][k]).
// ---------------------------------------------------------------------------
__global__ __launch_bounds__(256) void prep_kernel(
    const float* __restrict__ cw, const float* __restrict__ pw,
    float* __restrict__ wT1, char* __restrict__ wpk)
{
    int idx = blockIdx.x * 256 + threadIdx.x;
    if (idx < 81 * 256) {
        int k = idx >> 8, oc = idx & 255;
        wT1[idx] = cw[oc * 81 + k];
    }
    int Q = idx & 2047;
    int slab = idx >> 11;                 // 0..647
    int D = Q << 4;
    int R = D >> 9;                       // 0..63
    int v = (D & 511) ^ ((R & 31) << 4);
    int h = v >> 7, pl = (v >> 6) & 1, icb = v & 63;
    int ch = h * 64 + R;
    int g = slab / 81, k = slab - g * 81;
    int ic0 = g * 32 + (icb >> 1);
    const float* src = pw + ((size_t)ch * 256 + ic0) * 81 + k;
    v8s ov;
#pragma unroll
    for (int j = 0; j < 8; ++j) {
        unsigned short hh, ll; bf16split(src[(size_t)j * 81], hh, ll);
        ov[j] = (short)(pl ? ll : hh);
    }
    *(v8s*)(wpk + (size_t)slab * 32768 + D) = ov;
}

// ---------------------------------------------------------------------------
// conv1 (register-tiled): [B,1,28,28] -> xc2 rows of 1024 B [hi 256][lo 256]
// ---------------------------------------------------------------------------
__global__ __launch_bounds__(256) void conv1_kernel(
    const float* __restrict__ img,   // [B][784]
    const float* __restrict__ wT1,   // [81][256]
    const float* __restrict__ bias,  // [256]
    char* __restrict__ xc2,          // [bc][400][1024 B]
    int b0)
{
    const int bl = blockIdx.x;
    const int oc = threadIdx.x;
    __shared__ __align__(16) float im[784];
    const float* ib = img + (size_t)(b0 + bl) * 784;
    for (int e = oc; e < 784; e += 256) im[e] = ib[e];
    float w[81];
#pragma unroll
    for (int k = 0; k < 81; ++k) w[k] = wT1[k * 256 + oc];
    float bv = bias[oc];
    __syncthreads();
    char* ob = xc2 + (size_t)bl * 409600;
    for (int oy = 0; oy < 20; ++oy) {
        float a[20];
#pragma unroll
        for (int ox = 0; ox < 20; ++ox) a[ox] = bv;
        for (int ky = 0; ky < 9; ++ky) {
            const float* rp = &im[(oy + ky) * 28];
            float r[28];
#pragma unroll
            for (int q = 0; q < 7; ++q) {
                float4 v4 = *(const float4*)(rp + q * 4);
                r[q * 4] = v4.x; r[q * 4 + 1] = v4.y;
                r[q * 4 + 2] = v4.z; r[q * 4 + 3] = v4.w;
            }
#pragma unroll
            for (int kx = 0; kx < 9; ++kx) {
                float wv = w[ky * 9 + kx];
#pragma unroll
                for (int ox = 0; ox < 20; ++ox)
                    a[ox] = fmaf(wv, r[ox + kx], a[ox]);
            }
        }
#pragma unroll
        for (int ox = 0; ox < 20; ++ox) {
            float av = fmaxf(a[ox], 0.f);
            unsigned short h, l; bf16split(av, h, l);
            char* rp2 = ob + (size_t)(oy * 20 + ox) * 1024;
            *(unsigned short*)(rp2 + oc * 2) = h;
            *(unsigned short*)(rp2 + 512 + oc * 2) = l;
        }
    }
}

// ---------------------------------------------------------------------------
// primary conv implicit GEMM, split-bf16 (3 products), split-K x8, g-SLOWEST
// grid. BM=192 x BN=256, 8 waves, wave-tile 96x64. T3+T4, 2 PHASES/step
// (R16 structure with barrier count halved: 4 barriers/step):
// A double-buffered (2x24 KB) + B TRIPLE-buffered (3x32 KB) = 144 KB.
// Phase s = {6 A-reads + 4 B-reads ; stage portion ; s_barrier ; setprio(1);
// 18 MFMA ; setprio(0) ; s_barrier}. Step k issues A(k+1) (phase 0) and
// B(k+2) (phases 0-1); step-end wait vmcnt(4): A(k+1) drained (oldest 3),
// B(k+2)'s 4 loads ride across the barrier (same invariant as R16).
// ---------------------------------------------------------------------------
__global__ __launch_bounds__(512, 1) void gemm_kernel(
    const char* __restrict__ xc2,   // [bc][400][1024 B]
    const char* __restrict__ wpk,   // [648 slabs][32 KB]
    float* __restrict__ prim,       // [B*36][256], pre-zeroed
    int M, int Mtiles, int gm0)     // M = bc*36 local; gm0 = b0*36
{
    __shared__ __align__(128) char As[2][24576];
    __shared__ __align__(128) char Bs[3][32768];
    const int tid = threadIdx.x;
    const int w = tid >> 6, lane = tid & 63;
    const int wm = w & 1, wn = w >> 1;
    const int col = lane & 31, kg = lane >> 5;
    const int id = blockIdx.x;
    const int g = id / Mtiles;
    const int tile = id - g * Mtiles;
    const int m0 = tile * 192;

    // A-gather per-lane constants (3 GLDS of 1 KB per wave)
    int pbase[3], asrc[3];
#pragma unroll
    for (int i = 0; i < 3; ++i) {
        int d = (w * 3 + i) * 1024 + lane * 16;    // 0..24575
        int R = d >> 9;                            // 0..47
        int v = (d & 511) ^ ((R & 31) << 4);
        int h = v >> 7, pl = (v >> 6) & 1, icb = v & 63;
        int m = m0 + 48 * h + R; if (m >= M) m = M - 1;
        int b = m / 36, s6 = m - b * 36;
        pbase[i] = b * 400 + (s6 / 6) * 40 + (s6 % 6) * 2;
        asrc[i] = pl * 512 + g * 64 + icb;
    }
    // A fragment-read constants: m = wm*96 + fm*32 + col
    int Abase[3], Ahof[3], Axor[3];
#pragma unroll
    for (int fm = 0; fm < 3; ++fm) {
        int m = wm * 96 + fm * 32 + col;
        int h = m / 48, R = m - h * 48;
        Abase[fm] = R * 512;
        Ahof[fm] = h * 128;
        Axor[fm] = (R & 31) << 4;
    }
    const char* wg = wpk + (size_t)g * 81 * 32768;

    v16f acc[3][2];
#pragma unroll
    for (int i = 0; i < 3; ++i)
#pragma unroll
        for (int j = 0; j < 2; ++j)
#pragma unroll
            for (int e = 0; e < 16; ++e) acc[i][j][e] = 0.f;

    auto gldsA = [&](int nb, int kk, int i) {
        const int koff = (kk / 9) * 20 + (kk % 9);
        GLDS(xc2 + (size_t)(pbase[i] + koff) * 1024 + asrc[i],
             &As[nb][(w * 3 + i) * 1024]);
    };
    auto gldsB = [&](int nb, int kk, int i) {
        GLDS(wg + (size_t)kk * 32768 + (w * 4 + i) * 1024 + lane * 16,
             &Bs[nb][(w * 4 + i) * 1024]);
    };

    // prologue: A(0), B(0) needed for step 0; B(1) stays in flight
#pragma unroll
    for (int i = 0; i < 3; ++i) gldsA(0, 0, i);
#pragma unroll
    for (int i = 0; i < 4; ++i) gldsB(0, 0, i);
#pragma unroll
    for (int i = 0; i < 4; ++i) gldsB(1, 1, i);
    WAIT_VM4(); SCHED0();
    __builtin_amdgcn_s_barrier(); SCHED0();

    const int xr = col << 4;
    for (int k = 0; k < 81; ++k) {
        const char* Ab = &As[k & 1][0];
        const char* Bb = &Bs[k % 3][0];
        const int nA = (k + 1) & 1, nB = (k + 2) % 3;
        const bool stA = (k < 80), stB = (k < 79);

#pragma unroll
        for (int s = 0; s < 2; ++s) {
            const int vb = s * 32 + kg * 16;
            // phase fragment reads: 6 A + 4 B
            v8s Ah[3], Al[3], Bh[2], Bl[2];
#pragma unroll
            for (int fm = 0; fm < 3; ++fm) {
                const char* ap = Ab + Abase[fm];
                Ah[fm] = *(const v8s*)(ap + ((Ahof[fm] + vb) ^ Axor[fm]));
                Al[fm] = *(const v8s*)(ap + ((Ahof[fm] + 64 + vb) ^ Axor[fm]));
            }
#pragma unroll
            for (int fn = 0; fn < 2; ++fn) {
                const char* bp = Bb + (fn * 32 + col) * 512;
                Bh[fn] = *(const v8s*)(bp + ((wn * 128 + vb) ^ xr));
                Bl[fn] = *(const v8s*)(bp + ((wn * 128 + 64 + vb) ^ xr));
            }
            // stage portion (A(k+1) first -> oldest; B(k+2) last -> newest 4)
            if (s == 0) {
                if (stA) { gldsA(nA, k + 1, 0); gldsA(nA, k + 1, 1); gldsA(nA, k + 1, 2); }
                if (stB) gldsB(nB, k + 2, 0);
            } else {
                if (stB) { gldsB(nB, k + 2, 1); gldsB(nB, k + 2, 2); gldsB(nB, k + 2, 3); }
            }

            __builtin_amdgcn_s_barrier();
            SCHED0();
            __builtin_amdgcn_s_setprio(1);
#pragma unroll
            for (int fn = 0; fn < 2; ++fn)
#pragma unroll
                for (int fm = 0; fm < 3; ++fm) {
                    acc[fm][fn] = __builtin_amdgcn_mfma_f32_32x32x16_bf16(Al[fm], Bh[fn], acc[fm][fn], 0, 0, 0);
                    acc[fm][fn] = __builtin_amdgcn_mfma_f32_32x32x16_bf16(Ah[fm], Bl[fn], acc[fm][fn], 0, 0, 0);
                    acc[fm][fn] = __builtin_amdgcn_mfma_f32_32x32x16_bf16(Ah[fm], Bh[fn], acc[fm][fn], 0, 0, 0);
                }
            __builtin_amdgcn_s_setprio(0);
            SCHED0();
            if (s == 0) {
                __builtin_amdgcn_s_barrier();
            } else if (stA) {
                if (stB) { WAIT_VM4(); } else { WAIT_VM0(); }
                SCHED0();
                __builtin_amdgcn_s_barrier(); SCHED0();
            }
        }
    }

    // epilogue: atomic accumulate into the single prim plane (global m)
    float* pg = prim + (size_t)gm0 * 256;
#pragma unroll
    for (int fm = 0; fm < 3; ++fm)
#pragma unroll
        for (int fn = 0; fn < 2; ++fn) {
            int ch = wn * 64 + fn * 32 + col;
#pragma unroll
            for (int rg = 0; rg < 16; ++rg) {
                int row = (rg & 3) + 8 * (rg >> 2) + 4 * kg;
                int m = m0 + wm * 96 + fm * 32 + row;
                if (m < M) atomicAdd(&pg[(size_t)m * 256 + ch], acc[fm][fn][rg]);
            }
        }
}

// ---------------------------------------------------------------------------
// prim (1 plane, full batch) -> +bias -> regroup -> squash -> u [B][1152][8]
// ---------------------------------------------------------------------------
__global__ __launch_bounds__(256) void prim2u_kernel(
    const float* __restrict__ prim, const float* __restrict__ pb,
    float* __restrict__ u, int M)
{
    __shared__ float p[64 * 257];    // 65.8 KB
    __shared__ float bsh[256];
    const int tid = threadIdx.x;
    const int rows0 = blockIdx.x * 64;
    bsh[tid] = pb[tid];
#pragma unroll
    for (int j = 0; j < 16; ++j) {
        int e4 = j * 256 + tid;
        int row = e4 >> 6, c4 = (e4 & 63) << 2;
        int rr = rows0 + row; if (rr >= M) rr = M - 1;
        float4 a = *(const float4*)(prim + (size_t)rr * 256 + c4);
        float* pp = &p[row * 257 + c4];
        pp[0] = a.x; pp[1] = a.y; pp[2] = a.z; pp[3] = a.w;
    }
    __syncthreads();
#pragma unroll
    for (int j = 0; j < 8; ++j) {
        int idx = j * 256 + tid;          // 64 rows x 32 cc
        int row = idx & 63, cc = idx >> 6;
        int m = rows0 + row;
        if (m >= M) continue;
        int b = m / 36, s = m - b * 36;
        float p8[8]; float sn = 0.f;
#pragma unroll
        for (int d = 0; d < 8; ++d) {
            float v = p[row * 257 + d * 32 + cc] + bsh[d * 32 + cc];
            p8[d] = v; sn += v * v;
        }
        float fac = sqrtf(sn) / (1.0f + sn);
        float4 o0, o1;
        o0.x = fac * p8[0]; o0.y = fac * p8[1]; o0.z = fac * p8[2]; o0.w = fac * p8[3];
        o1.x = fac * p8[4]; o1.y = fac * p8[5]; o1.z = fac * p8[6]; o1.w = fac * p8[7];
        float* up = u + ((size_t)b * 1152 + cc * 36 + s) * 8;
        *(float4*)up = o0;
        *(float4*)(up + 4) = o1;
    }
}

// ---------------------------------------------------------------------------
// routing: c-major 1-D grid; one block per (b-pair, c), 512 thr, u_hat
// TRANSPOSED in LDS ([16][1152] per image, conflict-free).
// ---------------------------------------------------------------------------
__global__ __launch_bounds__(512) void routing_kernel(
    const float* __restrict__ u,   // [B][1152][8]
    const float* __restrict__ W,   // [10][1152][8][16]
    float* __restrict__ out,       // [B][10][16]
    int B, int npairs)
{
    const int id = blockIdx.x;
    const int c = id / npairs;
    const int pair = id - c * npairs;
    const int b0 = pair * 2;
    const int tid = threadIdx.x;
    __shared__ float uht[2][16][1152];    // 147456 B
    __shared__ float bijs[2][1152];       // 9216 B
    __shared__ float red[2][4 * 17];
    __shared__ float sred[2][17];
    __shared__ float mred[2][4];

    const float* __restrict__ Wc = W + (size_t)c * (1152 * 128);
    const int b1 = (b0 + 1 < B) ? b0 + 1 : b0;
    const float* __restrict__ ub0 = u + (size_t)b0 * 9216;
    const float* __restrict__ ub1 = u + (size_t)b1 * 9216;

    for (int n = tid; n < 1152; n += 512) {
        const float4* p0 = (const float4*)(ub0 + n * 8);
        const float4* p1 = (const float4*)(ub1 + n * 8);
        float4 a0 = p0[0], a1 = p0[1], c0 = p1[0], c1 = p1[1];
        float uu0[8] = {a0.x, a0.y, a0.z, a0.w, a1.x, a1.y, a1.z, a1.w};
        float uu1[8] = {c0.x, c0.y, c0.z, c0.w, c1.x, c1.y, c1.z, c1.w};
        float acc0[16], acc1[16];
#pragma unroll
        for (int o = 0; o < 16; ++o) { acc0[o] = 0.f; acc1[o] = 0.f; }
        const float* wn = Wc + n * 128;
#pragma unroll
        for (int i = 0; i < 8; ++i)
#pragma unroll
            for (int o = 0; o < 16; ++o) {
                float wv = wn[i * 16 + o];
                acc0[o] = fmaf(uu0[i], wv, acc0[o]);
                acc1[o] = fmaf(uu1[i], wv, acc1[o]);
            }
#pragma unroll
        for (int o = 0; o < 16; ++o) { uht[0][o][n] = acc0[o]; uht[1][o][n] = acc1[o]; }
        bijs[0][n] = 0.f; bijs[1][n] = 0.f;
    }
    __syncthreads();

    const int img = tid >> 8, t = tid & 255;
    const int wid = t >> 6, lane = t & 63;
    const float* __restrict__ UHT = &uht[img][0][0];
    float* __restrict__ bij = bijs[img];
    float* __restrict__ redi = red[img];
    float* __restrict__ sredi = sred[img];
    float* __restrict__ mredi = mred[img];

    float fac = 0.f, inv = 0.f;
    for (int it = 0; it < 3; ++it) {
        float m = -3.4e38f;
        for (int n = t; n < 1152; n += 256) m = fmaxf(m, bij[n]);
#pragma unroll
        for (int off = 32; off > 0; off >>= 1) m = fmaxf(m, __shfl_down(m, off));
        if (lane == 0) mredi[wid] = m;
        __syncthreads();
        float M = fmaxf(fmaxf(mredi[0], mredi[1]), fmaxf(mredi[2], mredi[3]));
        float se = 0.f;
        float sp[16];
#pragma unroll
        for (int o = 0; o < 16; ++o) sp[o] = 0.f;
        for (int n = t; n < 1152; n += 256) {
            float e = expf(bij[n] - M);
            se += e;
#pragma unroll
            for (int o = 0; o < 16; ++o) sp[o] = fmaf(e, UHT[o * 1152 + n], sp[o]);
        }
#pragma unroll
        for (int o = 0; o < 16; ++o)
#pragma unroll
            for (int off = 32; off > 0; off >>= 1) sp[o] += __shfl_down(sp[o], off);
#pragma unroll
        for (int off = 32; off > 0; off >>= 1) se += __shfl_down(se, off);
        if (lane == 0) {
#pragma unroll
            for (int o = 0; o < 16; ++o) redi[wid * 17 + o] = sp[o];
            redi[wid * 17 + 16] = se;
        }
        __syncthreads();
        if (t < 17)
            sredi[t] = redi[t] + redi[17 + t] + redi[34 + t] + redi[51 + t];
        __syncthreads();
        inv = 1.0f / sredi[16];
        float sn = 0.f;
        float sj[16];
#pragma unroll
        for (int o = 0; o < 16; ++o) { sj[o] = sredi[o] * inv; sn = fmaf(sj[o], sj[o], sn); }
        fac = sqrtf(sn) / (1.0f + sn);
        if (it < 2) {
            float v[16];
#pragma unroll
            for (int o = 0; o < 16; ++o) v[o] = fac * sj[o];
            for (int n = t; n < 1152; n += 256) {
                float a = 0.f;
#pragma unroll
                for (int o = 0; o < 16; ++o) a = fmaf(UHT[o * 1152 + n], v[o], a);
                bij[n] += a;
            }
        }
        __syncthreads();
    }
    if (t < 16 && b0 + img < B)
        out[((size_t)(b0 + img) * 10 + c) * 16 + t] = fac * (sredi[t] * inv);
}

// ---------------------------------------------------------------------------
extern "C" void kernel_launch(void* const* d_in, const int* in_sizes, int n_in,
                              void* d_out, int out_size, void* d_ws, size_t ws_size,
                              hipStream_t stream) {
    const float* images  = (const float*)d_in[0];
    const float* conv1_w = (const float*)d_in[1];
    const float* conv1_b = (const float*)d_in[2];
    const float* prim_w  = (const float*)d_in[3];
    const float* prim_b  = (const float*)d_in[4];
    const float* W       = (const float*)d_in[5];
    float* out = (float*)d_out;

    const int B = in_sizes[0] / 784;
    const int Mg = B * 36;
    const size_t usz = (size_t)B * 1152 * 8 * 4;      // 18.9 MB @ B=512
    const size_t xc2_full = (size_t)B * 409600;       // 209.7 MB @ B=512

    char* wsb = (char*)d_ws;
    size_t off = 0;
    float* wT1 = (float*)(wsb + off);
    off += 81 * 256 * 4;
    off = (off + 1023) & ~(size_t)1023;
    char* wpk = wsb + off;
    off += (size_t)648 * 32768;                  // 21.2 MB
    float* prim = (float*)(wsb + off);
    off += (size_t)Mg * 256 * 4;                 // 18.9 MB (whole batch)
    size_t rem = (ws_size > off) ? ws_size - off : 0;

    float* u;
    char* xc2base;
    int Bc;
    if (rem >= xc2_full) {
        // Single-pass: u ALIASES the xc2 region (xc2 dead after last gemm;
        // u first written by prim2u which runs after all gemms).
        xc2base = wsb + off;
        u = (float*)xc2base;
        Bc = B;
    } else {
        // Fallback: separate u, chunked xc2 (balanced, multiple of 16).
        u = (float*)(wsb + off);
        off += usz;
        rem = (ws_size > off) ? ws_size - off : 0;
        xc2base = wsb + off;
        long Bcmax = (long)(rem / 409600);
        if (Bcmax < 1) Bcmax = 1;
        if (Bcmax > B) Bcmax = B;
        int nch = (int)((B + Bcmax - 1) / Bcmax);
        Bc = (B + nch - 1) / nch;
        Bc = (Bc + 15) & ~15;
        if (Bc > Bcmax) Bc = (int)(Bcmax & ~15L);
        if (Bc < 1) Bc = (int)Bcmax;
    }

    hipMemsetAsync(prim, 0, (size_t)Mg * 256 * 4, stream);
    prep_kernel<<<5184, 256, 0, stream>>>(conv1_w, prim_w, wT1, wpk);

    for (int b0 = 0; b0 < B; b0 += Bc) {
        int bc = (B - b0 < Bc) ? (B - b0) : Bc;
        conv1_kernel<<<bc, 256, 0, stream>>>(images, wT1, conv1_b, xc2base, b0);
        int M = bc * 36;
        int Mtiles = (M + 191) / 192;
        gemm_kernel<<<Mtiles * 8, 512, 0, stream>>>(xc2base, wpk, prim, M, Mtiles, b0 * 36);
    }
    prim2u_kernel<<<(Mg + 63) / 64, 256, 0, stream>>>(prim, prim_b, u, Mg);
    int npairs = (B + 1) / 2;
    routing_kernel<<<npairs * 10, 512, 0, stream>>>(u, W, out, B, npairs);
}